// Round 3
// baseline (735.931 us; speedup 1.0000x reference)
//
#include <hip/hip_runtime.h>
#include <hip/hip_bf16.h>
#include <math.h>

// Problem constants (B=4, S=2048 -> T=8192, D=1024, E=8, K=2, H=2048)
#define T_TOK 8192
#define D_DIM 1024
#define E_NUM 8
#define H_DIM 2048

typedef __bf16 bf16;
typedef __bf16 bf16x8 __attribute__((ext_vector_type(8)));
typedef __bf16 bf16x4 __attribute__((ext_vector_type(4)));
typedef float  f32x4  __attribute__((ext_vector_type(4)));

// async global->LDS, 16 B per lane; LDS dest = wave-uniform base + lane*16
__device__ __forceinline__ void gload_lds16(const void* g, void* s) {
    __builtin_amdgcn_global_load_lds(
        (const __attribute__((address_space(1))) unsigned int*)g,
        (__attribute__((address_space(3))) unsigned int*)s, 16, 0, 0);
}

// ---------------------------------------------------------------- cvt_x
__global__ void cvt_x_kernel(const float* __restrict__ x, bf16* __restrict__ xb) {
    int i = blockIdx.x * blockDim.x + threadIdx.x;
    const float4* xp = (const float4*)x;
    float4 a = xp[i * 2];
    float4 b = xp[i * 2 + 1];
    bf16x8 o;
    o[0] = (bf16)a.x; o[1] = (bf16)a.y; o[2] = (bf16)a.z; o[3] = (bf16)a.w;
    o[4] = (bf16)b.x; o[5] = (bf16)b.y; o[6] = (bf16)b.z; o[7] = (bf16)b.w;
    *(bf16x8*)(xb + (size_t)i * 8) = o;
}

// ---------------------------------------------------------------- transpose
// W [E][K][N] fp32  ->  Wt [E][N][K] bf16.  32x32 tiles via LDS.
template <int K, int N>
__global__ void transpose_kernel(const float* __restrict__ W, bf16* __restrict__ Wt) {
    const int e  = blockIdx.z;
    const int kb = blockIdx.y * 32;
    const int nb = blockIdx.x * 32;
    __shared__ float tile[32][33];
    const float* We  = W  + (size_t)e * K * N;
    bf16*        Wte = Wt + (size_t)e * N * K;
    const int tid = threadIdx.x;
    const int r  = tid >> 3;        // 0..31
    const int c4 = (tid & 7) * 4;   // 0..28
    float4 v = *(const float4*)(We + (size_t)(kb + r) * N + nb + c4);
    tile[r][c4 + 0] = v.x; tile[r][c4 + 1] = v.y;
    tile[r][c4 + 2] = v.z; tile[r][c4 + 3] = v.w;
    __syncthreads();
    const int rn = tid >> 3;        // n within tile
    const int k4 = (tid & 7) * 4;   // k within tile
    bf16x4 o;
    o[0] = (bf16)tile[k4 + 0][rn]; o[1] = (bf16)tile[k4 + 1][rn];
    o[2] = (bf16)tile[k4 + 2][rn]; o[3] = (bf16)tile[k4 + 3][rn];
    *(bf16x4*)(Wte + (size_t)(nb + rn) * K + kb + k4) = o;
}

// ---------------------------------------------------------------- gating
// Block = 4 waves = 4 tokens. Lane l: expert e = l&7, d-slice s = l>>3,
// d = i*8 + s. ONE fp64 accumulator pair per lane (no spill — round-2's
// double acc[8] spilled to scratch: VGPR_Count=20, 200us).
// x rows staged to LDS (coalesced); gw reads are 256B contiguous per instr;
// LDS dot reads are 8-bank x 8-lane-broadcast, conflict-free.
// fp64 keeps top-2 selection exact vs the numpy reference.
__global__ __launch_bounds__(256) void gating_kernel(
    const float* __restrict__ x, const float* __restrict__ gw,
    const float* __restrict__ gb, int* __restrict__ counts,
    int* __restrict__ eIdx, float* __restrict__ wgt) {
    __shared__ float xs[4 * D_DIM];
    const int tid  = threadIdx.x;
    const int wave = tid >> 6;
    const int lane = tid & 63;
    // stage 4 token rows (16 KB) coalesced
    {
        const float4* src = (const float4*)(x + (size_t)blockIdx.x * 4 * D_DIM);
        float4* dst = (float4*)xs;
#pragma unroll
        for (int k = 0; k < 4; k++) dst[tid + k * 256] = src[tid + k * 256];
    }
    __syncthreads();

    const int e = lane & 7;
    const int s = lane >> 3;
    const float* xw = xs + wave * D_DIM;
    double acc_a = 0.0, acc_b = 0.0;
#pragma unroll 8
    for (int i = 0; i < 128; i += 2) {
        int d0 = i * 8 + s;
        int d1 = (i + 1) * 8 + s;
        acc_a += (double)xw[d0] * (double)gw[d0 * 8 + e];
        acc_b += (double)xw[d1] * (double)gw[d1 * 8 + e];
    }
    double acc = acc_a + acc_b;
    // reduce across the 8 s-slices (lanes l, l^8, l^16, l^32)
    acc += __shfl_xor(acc, 8, 64);
    acc += __shfl_xor(acc, 16, 64);
    acc += __shfl_xor(acc, 32, 64);
    // lane e (e<8) now holds logit[e]; gather to lane 0 via shfl
    double lg[E_NUM];
#pragma unroll
    for (int k = 0; k < E_NUM; k++) lg[k] = __shfl(acc, k, 64);

    if (lane == 0) {
        int token = blockIdx.x * 4 + wave;
        double v[E_NUM], p[E_NUM];
        double mx = -1e300;
#pragma unroll
        for (int k = 0; k < E_NUM; k++) { v[k] = lg[k] + (double)gb[k]; mx = fmax(mx, v[k]); }
        double sum = 0.0;
#pragma unroll
        for (int k = 0; k < E_NUM; k++) { p[k] = exp(v[k] - mx); sum += p[k]; }
        int i0 = 0; double p0 = p[0];
#pragma unroll
        for (int k = 1; k < E_NUM; k++) if (p[k] > p0) { p0 = p[k]; i0 = k; }
        int i1 = -1; double p1 = -1.0;
#pragma unroll
        for (int k = 0; k < E_NUM; k++) if (k != i0 && p[k] > p1) { p1 = p[k]; i1 = k; }
        double q0 = p0 / sum, q1 = p1 / sum;
        double sw = q0 + q1 + 1e-9;
        eIdx[token * 2]     = i0;
        eIdx[token * 2 + 1] = i1;
        wgt[token * 2]      = (float)(q0 / sw);
        wgt[token * 2 + 1]  = (float)(q1 / sw);
        atomicAdd(&counts[i0], 1);
        atomicAdd(&counts[i1], 1);
    }
}

// ---------------------------------------------------------------- scan
__global__ void scan_kernel(const int* __restrict__ counts, int* __restrict__ offsets) {
    if (threadIdx.x == 0) {
        int s = 0;
        for (int e = 0; e < E_NUM; e++) { offsets[e] = s; s += counts[e]; }
    }
}

// ---------------------------------------------------------------- scatter
__global__ void scatter_kernel(const int* __restrict__ eIdx, const int* __restrict__ offsets,
                               int* __restrict__ fill, int* __restrict__ rowIdx,
                               int* __restrict__ slot) {
    int t = blockIdx.x * blockDim.x + threadIdx.x;
    if (t >= T_TOK) return;
#pragma unroll
    for (int k = 0; k < 2; k++) {
        int e = eIdx[t * 2 + k];
        int pos = atomicAdd(&fill[e], 1);
        int r = offsets[e] + pos;
        rowIdx[r] = t;
        slot[t * 2 + k] = r;
    }
}

// ---------------------------------------------------------------- grouped GEMM
// C[r,n] = act( sum_k A[r,k] * Bt[e][n,k] + bias[e][n] ) on expert-e's compact
// row segment. A bf16 row-major; Bt bf16 [N][K] (pre-transposed weights).
// m97 structure: 128x128x32 tile, global_load_lds dwordx4 staging for A and B,
// 4 waves x 4x4 of 16x16x32 bf16 MFMA.
template <int KD, int ND, bool RELU, bool GATHER>
__global__ __launch_bounds__(256, 2) void moe_gemm_kernel(
    const bf16* __restrict__ A, const bf16* __restrict__ Bt,
    const float* __restrict__ bias, bf16* __restrict__ Out,
    const int* __restrict__ counts, const int* __restrict__ offsets,
    const int* __restrict__ rowIdx) {
    const int e  = blockIdx.z;
    const int Ne = counts[e];
    const int rb = blockIdx.y;
    if (rb * 128 >= Ne) return;
    const int base = offsets[e];
    const int n0   = blockIdx.x * 128;
    const bf16*  Be = Bt + (size_t)e * KD * ND;  // [ND][KD]
    const float* be = bias + (size_t)e * ND;

    __shared__ bf16 As[128 * 32];  // [m][k], unpadded (required by global_load_lds)
    __shared__ bf16 Bs[128 * 32];  // [n][k]

    const int tid  = threadIdx.x;
    const int wave = tid >> 6;
    const int lane = tid & 63;

    const int srow  = wave * 16 + (lane >> 2);
    const int skoff = (lane & 3) * 8;
    int m0g = rb * 128 + srow;      if (m0g >= Ne) m0g = Ne - 1;  // clamp: extra rows
    int m1g = rb * 128 + 64 + srow; if (m1g >= Ne) m1g = Ne - 1;  // computed, not stored
    const bf16 *aA0, *aA1;
    if (GATHER) {
        aA0 = A + (size_t)rowIdx[base + m0g] * KD + skoff;
        aA1 = A + (size_t)rowIdx[base + m1g] * KD + skoff;
    } else {
        aA0 = A + (size_t)(base + m0g) * KD + skoff;
        aA1 = A + (size_t)(base + m1g) * KD + skoff;
    }
    const bf16* bB0 = Be + (size_t)(n0 + srow) * KD + skoff;
    const bf16* bB1 = Be + (size_t)(n0 + 64 + srow) * KD + skoff;
    char* dstA0 = (char*)As + wave * 1024;
    char* dstA1 = (char*)As + 4096 + wave * 1024;
    char* dstB0 = (char*)Bs + wave * 1024;
    char* dstB1 = (char*)Bs + 4096 + wave * 1024;

    const int wm = (wave >> 1) * 64;
    const int wn = (wave & 1) * 64;
    const int lrow = lane & 15;
    const int quad = lane >> 4;

    f32x4 acc[4][4] = {};

    for (int k0 = 0; k0 < KD; k0 += 32) {
        gload_lds16(aA0 + k0, dstA0);
        gload_lds16(aA1 + k0, dstA1);
        gload_lds16(bB0 + k0, dstB0);
        gload_lds16(bB1 + k0, dstB1);
        __syncthreads();  // drains vmcnt -> LDS tiles complete

        bf16x8 af[4], bfv[4];
#pragma unroll
        for (int t4 = 0; t4 < 4; t4++)
            af[t4] = *(const bf16x8*)&As[(wm + t4 * 16 + lrow) * 32 + quad * 8];
#pragma unroll
        for (int t4 = 0; t4 < 4; t4++)
            bfv[t4] = *(const bf16x8*)&Bs[(wn + t4 * 16 + lrow) * 32 + quad * 8];
#pragma unroll
        for (int ti = 0; ti < 4; ti++)
#pragma unroll
            for (int tj = 0; tj < 4; tj++)
                acc[ti][tj] = __builtin_amdgcn_mfma_f32_16x16x32_bf16(
                    af[ti], bfv[tj], acc[ti][tj], 0, 0, 0);
        __syncthreads();
    }

    // epilogue: C/D layout col = lane&15, row = quad*4 + reg
#pragma unroll
    for (int ti = 0; ti < 4; ti++) {
        int rloc = wm + ti * 16 + quad * 4;
#pragma unroll
        for (int tj = 0; tj < 4; tj++) {
            int gcol = n0 + wn + tj * 16 + lrow;
            float bb = be[gcol];
#pragma unroll
            for (int r = 0; r < 4; r++) {
                int grow = rb * 128 + rloc + r;
                if (grow < Ne) {
                    float v = acc[ti][tj][r] + bb;
                    if (RELU) v = v > 0.f ? v : 0.f;
                    Out[(size_t)(base + grow) * ND + gcol] = (bf16)v;
                }
            }
        }
    }
}

// ---------------------------------------------------------------- combine
__global__ void combine_kernel(const bf16* __restrict__ Yb, const int* __restrict__ slot,
                               const float* __restrict__ wgt, float* __restrict__ out) {
    int t = blockIdx.x;
    int d = threadIdx.x * 4;
    int s0 = slot[t * 2], s1 = slot[t * 2 + 1];
    float w0 = wgt[t * 2], w1 = wgt[t * 2 + 1];
    bf16x4 y0 = *(const bf16x4*)(Yb + (size_t)s0 * D_DIM + d);
    bf16x4 y1 = *(const bf16x4*)(Yb + (size_t)s1 * D_DIM + d);
    float4 o;
    o.x = w0 * (float)y0[0] + w1 * (float)y1[0];
    o.y = w0 * (float)y0[1] + w1 * (float)y1[1];
    o.z = w0 * (float)y0[2] + w1 * (float)y1[2];
    o.w = w0 * (float)y0[3] + w1 * (float)y1[3];
    *(float4*)(out + (size_t)t * D_DIM + d) = o;
}

// ---------------------------------------------------------------- launch
extern "C" void kernel_launch(void* const* d_in, const int* in_sizes, int n_in,
                              void* d_out, int out_size, void* d_ws, size_t ws_size,
                              hipStream_t stream) {
    const float* x  = (const float*)d_in[0];
    const float* gw = (const float*)d_in[1];
    const float* gb = (const float*)d_in[2];
    const float* w1 = (const float*)d_in[3];
    const float* b1 = (const float*)d_in[4];
    const float* w2 = (const float*)d_in[5];
    const float* b2 = (const float*)d_in[6];
    float* out = (float*)d_out;

    char* ws = (char*)d_ws;
    // layout:
    //   [0,96)            counts[8] / fill[8] / offsets[8]
    //   [256, +4*64K)     eIdx, wgt, slot, rowIdx
    //   @262400           Xb   bf16 T*D               (16 MiB)
    //   @17039616         Hb   bf16 T*2*H             (64 MiB)
    //   @84148480         W2t  bf16 E*D*H             (32 MiB)
    //   @117702912        W1t  bf16 E*H*D  (aliases Yb: W1t dead after GEMM1,
    //                     Yb written by GEMM2)        (32 MiB)
    int*   counts = (int*)ws;
    int*   fill   = (int*)(ws + 32);
    int*   offs   = (int*)(ws + 64);
    int*   eIdx   = (int*)(ws + 256);
    float* wgt    = (float*)(ws + 256 + 65536);
    int*   slot   = (int*)(ws + 256 + 2 * 65536);
    int*   rowIdx = (int*)(ws + 256 + 3 * 65536);
    bf16*  Xb  = (bf16*)(ws + 262400);
    bf16*  Hb  = (bf16*)(ws + 17039616);
    bf16*  W2t = (bf16*)(ws + 84148480);
    bf16*  W1t = (bf16*)(ws + 117702912);
    bf16*  Yb  = W1t;  // alias (see above)

    if (ws_size < (size_t)151257344) return;

    hipMemsetAsync(ws, 0, 64, stream);  // counts + fill
    cvt_x_kernel<<<(T_TOK * D_DIM) / (256 * 8), 256, 0, stream>>>(x, Xb);
    // w1 [E][D][H] -> W1t [E][H][D];  w2 [E][H][D] -> W2t [E][D][H]
    transpose_kernel<D_DIM, H_DIM>
        <<<dim3(H_DIM / 32, D_DIM / 32, E_NUM), 256, 0, stream>>>(w1, W1t);
    transpose_kernel<H_DIM, D_DIM>
        <<<dim3(D_DIM / 32, H_DIM / 32, E_NUM), 256, 0, stream>>>(w2, W2t);
    gating_kernel<<<T_TOK / 4, 256, 0, stream>>>(x, gw, gb, counts, eIdx, wgt);
    scan_kernel<<<1, 64, 0, stream>>>(counts, offs);
    scatter_kernel<<<T_TOK / 256, 256, 0, stream>>>(eIdx, offs, fill, rowIdx, slot);
    // GEMM1: h = relu(x_gathered @ W1 + b1)   [rows, 2048], K=1024
    moe_gemm_kernel<D_DIM, H_DIM, true, true>
        <<<dim3(H_DIM / 128, T_TOK / 128, E_NUM), 256, 0, stream>>>(
            Xb, W1t, b1, Hb, counts, offs, rowIdx);
    // GEMM2: y = h @ W2 + b2   [rows, 1024], K=2048
    moe_gemm_kernel<H_DIM, D_DIM, false, false>
        <<<dim3(D_DIM / 128, T_TOK / 128, E_NUM), 256, 0, stream>>>(
            Hb, W2t, b2, Yb, counts, offs, (const int*)nullptr);
    combine_kernel<<<T_TOK, 256, 0, stream>>>(Yb, slot, wgt, out);
}

// Round 4
// 472.108 us; speedup vs baseline: 1.5588x; 1.5588x over previous
//
#include <hip/hip_runtime.h>
#include <hip/hip_bf16.h>
#include <math.h>

// Problem constants (B=4, S=2048 -> T=8192, D=1024, E=8, K=2, H=2048)
#define T_TOK 8192
#define D_DIM 1024
#define E_NUM 8
#define H_DIM 2048

typedef __bf16 bf16;
typedef __bf16 bf16x8 __attribute__((ext_vector_type(8)));
typedef __bf16 bf16x4 __attribute__((ext_vector_type(4)));
typedef float  f32x4  __attribute__((ext_vector_type(4)));

// async global->LDS, 16 B per lane; LDS dest = wave-uniform base + lane*16
__device__ __forceinline__ void gload_lds16(const void* g, void* s) {
    __builtin_amdgcn_global_load_lds(
        (const __attribute__((address_space(1))) unsigned int*)g,
        (__attribute__((address_space(3))) unsigned int*)s, 16, 0, 0);
}

// ---------------------------------------------------------------- cvt_x
__global__ void cvt_x_kernel(const float* __restrict__ x, bf16* __restrict__ xb) {
    int i = blockIdx.x * blockDim.x + threadIdx.x;
    const float4* xp = (const float4*)x;
    float4 a = xp[i * 2];
    float4 b = xp[i * 2 + 1];
    bf16x8 o;
    o[0] = (bf16)a.x; o[1] = (bf16)a.y; o[2] = (bf16)a.z; o[3] = (bf16)a.w;
    o[4] = (bf16)b.x; o[5] = (bf16)b.y; o[6] = (bf16)b.z; o[7] = (bf16)b.w;
    *(bf16x8*)(xb + (size_t)i * 8) = o;
}

// ---------------------------------------------------------------- transpose
// W [E][K][N] fp32  ->  Wt [E][N][K] bf16.  32x32 tiles via LDS.
template <int K, int N>
__global__ void transpose_kernel(const float* __restrict__ W, bf16* __restrict__ Wt) {
    const int e  = blockIdx.z;
    const int kb = blockIdx.y * 32;
    const int nb = blockIdx.x * 32;
    __shared__ float tile[32][33];
    const float* We  = W  + (size_t)e * K * N;
    bf16*        Wte = Wt + (size_t)e * N * K;
    const int tid = threadIdx.x;
    const int r  = tid >> 3;        // 0..31
    const int c4 = (tid & 7) * 4;   // 0..28
    float4 v = *(const float4*)(We + (size_t)(kb + r) * N + nb + c4);
    tile[r][c4 + 0] = v.x; tile[r][c4 + 1] = v.y;
    tile[r][c4 + 2] = v.z; tile[r][c4 + 3] = v.w;
    __syncthreads();
    const int rn = tid >> 3;        // n within tile
    const int k4 = (tid & 7) * 4;   // k within tile
    bf16x4 o;
    o[0] = (bf16)tile[k4 + 0][rn]; o[1] = (bf16)tile[k4 + 1][rn];
    o[2] = (bf16)tile[k4 + 2][rn]; o[3] = (bf16)tile[k4 + 3][rn];
    *(bf16x4*)(Wte + (size_t)(nb + rn) * K + kb + k4) = o;
}

// ---------------------------------------------------------------- gating
// Block = 4 waves = 4 tokens. Lane l: expert e = l&7, d-slice s = l>>3.
// NO GLOBAL ATOMICS: rounds 1-3 did 16384 atomicAdds into counts[8] (one
// cache line -> one L2 slice, fully serialized ~29cyc each = ~198us, the
// exact measured 199.7us plateau). Counts now come from count_kernel.
__global__ __launch_bounds__(256) void gating_kernel(
    const float* __restrict__ x, const float* __restrict__ gw,
    const float* __restrict__ gb,
    int* __restrict__ eIdx, float* __restrict__ wgt) {
    __shared__ float xs[4 * D_DIM];
    const int tid  = threadIdx.x;
    const int wave = tid >> 6;
    const int lane = tid & 63;
    {
        const float4* src = (const float4*)(x + (size_t)blockIdx.x * 4 * D_DIM);
        float4* dst = (float4*)xs;
#pragma unroll
        for (int k = 0; k < 4; k++) dst[tid + k * 256] = src[tid + k * 256];
    }
    __syncthreads();

    const int e = lane & 7;
    const int s = lane >> 3;
    const float* xw = xs + wave * D_DIM;
    double acc_a = 0.0, acc_b = 0.0;
#pragma unroll 8
    for (int i = 0; i < 128; i += 2) {
        int d0 = i * 8 + s;
        int d1 = (i + 1) * 8 + s;
        acc_a += (double)xw[d0] * (double)gw[d0 * 8 + e];
        acc_b += (double)xw[d1] * (double)gw[d1 * 8 + e];
    }
    double acc = acc_a + acc_b;
    acc += __shfl_xor(acc, 8, 64);
    acc += __shfl_xor(acc, 16, 64);
    acc += __shfl_xor(acc, 32, 64);
    double lg[E_NUM];
#pragma unroll
    for (int k = 0; k < E_NUM; k++) lg[k] = __shfl(acc, k, 64);

    if (lane == 0) {
        int token = blockIdx.x * 4 + wave;
        double v[E_NUM], p[E_NUM];
        double mx = -1e300;
#pragma unroll
        for (int k = 0; k < E_NUM; k++) { v[k] = lg[k] + (double)gb[k]; mx = fmax(mx, v[k]); }
        double sum = 0.0;
#pragma unroll
        for (int k = 0; k < E_NUM; k++) { p[k] = exp(v[k] - mx); sum += p[k]; }
        int i0 = 0; double p0 = p[0];
#pragma unroll
        for (int k = 1; k < E_NUM; k++) if (p[k] > p0) { p0 = p[k]; i0 = k; }
        int i1 = -1; double p1 = -1.0;
#pragma unroll
        for (int k = 0; k < E_NUM; k++) if (k != i0 && p[k] > p1) { p1 = p[k]; i1 = k; }
        double q0 = p0 / sum, q1 = p1 / sum;
        double sw = q0 + q1 + 1e-9;
        eIdx[token * 2]     = i0;
        eIdx[token * 2 + 1] = i1;
        wgt[token * 2]      = (float)(q0 / sw);
        wgt[token * 2 + 1]  = (float)(q1 / sw);
    }
}

// ---------------------------------------------------------------- count
// 32 blocks x 256 threads; each thread reads 2 eIdx entries. LDS histogram
// per block, then 8 global atomics per block (256 total vs 16384 before).
__global__ void count_kernel(const int* __restrict__ eIdx, int* __restrict__ counts) {
    __shared__ int bc[E_NUM];
    const int tid = threadIdx.x;
    if (tid < E_NUM) bc[tid] = 0;
    __syncthreads();
    int2 ev = *(const int2*)(eIdx + (size_t)blockIdx.x * 512 + tid * 2);
    atomicAdd(&bc[ev.x], 1);
    atomicAdd(&bc[ev.y], 1);
    __syncthreads();
    if (tid < E_NUM) atomicAdd(&counts[tid], bc[tid]);
}

// ---------------------------------------------------------------- scan
__global__ void scan_kernel(const int* __restrict__ counts, int* __restrict__ offsets) {
    if (threadIdx.x == 0) {
        int s = 0;
        for (int e = 0; e < E_NUM; e++) { offsets[e] = s; s += counts[e]; }
    }
}

// ---------------------------------------------------------------- scatter
// 32 blocks x 256 threads, 512 tokens (1024 entries) per block.
// LDS histogram -> one global atomicAdd per expert per block (256 total)
// -> LDS cursor for intra-block rank. No contended global atomics.
__global__ void scatter_kernel(const int* __restrict__ eIdx, const int* __restrict__ offsets,
                               int* __restrict__ fill, int* __restrict__ rowIdx,
                               int* __restrict__ slot) {
    __shared__ int bc[E_NUM];
    __shared__ int bbase[E_NUM];
    __shared__ int bcur[E_NUM];
    const int tid = threadIdx.x;
    if (tid < E_NUM) { bc[tid] = 0; bcur[tid] = 0; }
    __syncthreads();
    int t0 = blockIdx.x * 512 + tid * 2;  // two tokens per thread
    int4 ev = *(const int4*)(eIdx + (size_t)t0 * 2);
    atomicAdd(&bc[ev.x], 1);
    atomicAdd(&bc[ev.y], 1);
    atomicAdd(&bc[ev.z], 1);
    atomicAdd(&bc[ev.w], 1);
    __syncthreads();
    if (tid < E_NUM) bbase[tid] = atomicAdd(&fill[tid], bc[tid]);
    __syncthreads();
    int p0 = atomicAdd(&bcur[ev.x], 1);
    int r0 = offsets[ev.x] + bbase[ev.x] + p0;
    rowIdx[r0] = t0; slot[t0 * 2] = r0;
    int p1 = atomicAdd(&bcur[ev.y], 1);
    int r1 = offsets[ev.y] + bbase[ev.y] + p1;
    rowIdx[r1] = t0; slot[t0 * 2 + 1] = r1;
    int p2 = atomicAdd(&bcur[ev.z], 1);
    int r2 = offsets[ev.z] + bbase[ev.z] + p2;
    rowIdx[r2] = t0 + 1; slot[(t0 + 1) * 2] = r2;
    int p3 = atomicAdd(&bcur[ev.w], 1);
    int r3 = offsets[ev.w] + bbase[ev.w] + p3;
    rowIdx[r3] = t0 + 1; slot[(t0 + 1) * 2 + 1] = r3;
}

// ---------------------------------------------------------------- grouped GEMM
// C[r,n] = act( sum_k A[r,k] * Bt[e][n,k] + bias[e][n] ) on expert-e's compact
// row segment. A bf16 row-major; Bt bf16 [N][K] (pre-transposed weights).
// m97 structure: 128x128x32 tile, global_load_lds dwordx4 staging for A and B,
// 4 waves x 4x4 of 16x16x32 bf16 MFMA.
template <int KD, int ND, bool RELU, bool GATHER>
__global__ __launch_bounds__(256, 2) void moe_gemm_kernel(
    const bf16* __restrict__ A, const bf16* __restrict__ Bt,
    const float* __restrict__ bias, bf16* __restrict__ Out,
    const int* __restrict__ counts, const int* __restrict__ offsets,
    const int* __restrict__ rowIdx) {
    const int e  = blockIdx.z;
    const int Ne = counts[e];
    const int rb = blockIdx.y;
    if (rb * 128 >= Ne) return;
    const int base = offsets[e];
    const int n0   = blockIdx.x * 128;
    const bf16*  Be = Bt + (size_t)e * KD * ND;  // [ND][KD]
    const float* be = bias + (size_t)e * ND;

    __shared__ bf16 As[128 * 32];  // [m][k], unpadded (required by global_load_lds)
    __shared__ bf16 Bs[128 * 32];  // [n][k]

    const int tid  = threadIdx.x;
    const int wave = tid >> 6;
    const int lane = tid & 63;

    const int srow  = wave * 16 + (lane >> 2);
    const int skoff = (lane & 3) * 8;
    int m0g = rb * 128 + srow;      if (m0g >= Ne) m0g = Ne - 1;  // clamp: extra rows
    int m1g = rb * 128 + 64 + srow; if (m1g >= Ne) m1g = Ne - 1;  // computed, not stored
    const bf16 *aA0, *aA1;
    if (GATHER) {
        aA0 = A + (size_t)rowIdx[base + m0g] * KD + skoff;
        aA1 = A + (size_t)rowIdx[base + m1g] * KD + skoff;
    } else {
        aA0 = A + (size_t)(base + m0g) * KD + skoff;
        aA1 = A + (size_t)(base + m1g) * KD + skoff;
    }
    const bf16* bB0 = Be + (size_t)(n0 + srow) * KD + skoff;
    const bf16* bB1 = Be + (size_t)(n0 + 64 + srow) * KD + skoff;
    char* dstA0 = (char*)As + wave * 1024;
    char* dstA1 = (char*)As + 4096 + wave * 1024;
    char* dstB0 = (char*)Bs + wave * 1024;
    char* dstB1 = (char*)Bs + 4096 + wave * 1024;

    const int wm = (wave >> 1) * 64;
    const int wn = (wave & 1) * 64;
    const int lrow = lane & 15;
    const int quad = lane >> 4;

    f32x4 acc[4][4] = {};

    for (int k0 = 0; k0 < KD; k0 += 32) {
        gload_lds16(aA0 + k0, dstA0);
        gload_lds16(aA1 + k0, dstA1);
        gload_lds16(bB0 + k0, dstB0);
        gload_lds16(bB1 + k0, dstB1);
        __syncthreads();  // drains vmcnt -> LDS tiles complete

        bf16x8 af[4], bfv[4];
#pragma unroll
        for (int t4 = 0; t4 < 4; t4++)
            af[t4] = *(const bf16x8*)&As[(wm + t4 * 16 + lrow) * 32 + quad * 8];
#pragma unroll
        for (int t4 = 0; t4 < 4; t4++)
            bfv[t4] = *(const bf16x8*)&Bs[(wn + t4 * 16 + lrow) * 32 + quad * 8];
#pragma unroll
        for (int ti = 0; ti < 4; ti++)
#pragma unroll
            for (int tj = 0; tj < 4; tj++)
                acc[ti][tj] = __builtin_amdgcn_mfma_f32_16x16x32_bf16(
                    af[ti], bfv[tj], acc[ti][tj], 0, 0, 0);
        __syncthreads();
    }

    // epilogue: C/D layout col = lane&15, row = quad*4 + reg
#pragma unroll
    for (int ti = 0; ti < 4; ti++) {
        int rloc = wm + ti * 16 + quad * 4;
#pragma unroll
        for (int tj = 0; tj < 4; tj++) {
            int gcol = n0 + wn + tj * 16 + lrow;
            float bb = be[gcol];
#pragma unroll
            for (int r = 0; r < 4; r++) {
                int grow = rb * 128 + rloc + r;
                if (grow < Ne) {
                    float v = acc[ti][tj][r] + bb;
                    if (RELU) v = v > 0.f ? v : 0.f;
                    Out[(size_t)(base + grow) * ND + gcol] = (bf16)v;
                }
            }
        }
    }
}

// ---------------------------------------------------------------- combine
__global__ void combine_kernel(const bf16* __restrict__ Yb, const int* __restrict__ slot,
                               const float* __restrict__ wgt, float* __restrict__ out) {
    int t = blockIdx.x;
    int d = threadIdx.x * 4;
    int s0 = slot[t * 2], s1 = slot[t * 2 + 1];
    float w0 = wgt[t * 2], w1 = wgt[t * 2 + 1];
    bf16x4 y0 = *(const bf16x4*)(Yb + (size_t)s0 * D_DIM + d);
    bf16x4 y1 = *(const bf16x4*)(Yb + (size_t)s1 * D_DIM + d);
    float4 o;
    o.x = w0 * (float)y0[0] + w1 * (float)y1[0];
    o.y = w0 * (float)y0[1] + w1 * (float)y1[1];
    o.z = w0 * (float)y0[2] + w1 * (float)y1[2];
    o.w = w0 * (float)y0[3] + w1 * (float)y1[3];
    *(float4*)(out + (size_t)t * D_DIM + d) = o;
}

// ---------------------------------------------------------------- launch
extern "C" void kernel_launch(void* const* d_in, const int* in_sizes, int n_in,
                              void* d_out, int out_size, void* d_ws, size_t ws_size,
                              hipStream_t stream) {
    const float* x  = (const float*)d_in[0];
    const float* gw = (const float*)d_in[1];
    const float* gb = (const float*)d_in[2];
    const float* w1 = (const float*)d_in[3];
    const float* b1 = (const float*)d_in[4];
    const float* w2 = (const float*)d_in[5];
    const float* b2 = (const float*)d_in[6];
    float* out = (float*)d_out;

    char* ws = (char*)d_ws;
    // layout:
    //   [0,96)            counts[8] / fill[8] / offsets[8]
    //   [256, +4*64K)     eIdx, wgt, slot, rowIdx
    //   @262400           Xb   bf16 T*D               (16 MiB)
    //   @17039616         Hb   bf16 T*2*H             (64 MiB)
    //   @84148480         W2t  bf16 E*D*H             (32 MiB)
    //   @117702912        W1t  bf16 E*H*D  (aliases Yb: W1t dead after GEMM1,
    //                     Yb written by GEMM2)        (32 MiB)
    int*   counts = (int*)ws;
    int*   fill   = (int*)(ws + 32);
    int*   offs   = (int*)(ws + 64);
    int*   eIdx   = (int*)(ws + 256);
    float* wgt    = (float*)(ws + 256 + 65536);
    int*   slot   = (int*)(ws + 256 + 2 * 65536);
    int*   rowIdx = (int*)(ws + 256 + 3 * 65536);
    bf16*  Xb  = (bf16*)(ws + 262400);
    bf16*  Hb  = (bf16*)(ws + 17039616);
    bf16*  W2t = (bf16*)(ws + 84148480);
    bf16*  W1t = (bf16*)(ws + 117702912);
    bf16*  Yb  = W1t;  // alias (see above)

    if (ws_size < (size_t)151257344) return;

    hipMemsetAsync(ws, 0, 64, stream);  // counts + fill
    cvt_x_kernel<<<(T_TOK * D_DIM) / (256 * 8), 256, 0, stream>>>(x, Xb);
    // w1 [E][D][H] -> W1t [E][H][D];  w2 [E][H][D] -> W2t [E][D][H]
    transpose_kernel<D_DIM, H_DIM>
        <<<dim3(H_DIM / 32, D_DIM / 32, E_NUM), 256, 0, stream>>>(w1, W1t);
    transpose_kernel<H_DIM, D_DIM>
        <<<dim3(D_DIM / 32, H_DIM / 32, E_NUM), 256, 0, stream>>>(w2, W2t);
    gating_kernel<<<T_TOK / 4, 256, 0, stream>>>(x, gw, gb, eIdx, wgt);
    count_kernel<<<T_TOK * 2 / 512, 256, 0, stream>>>(eIdx, counts);
    scan_kernel<<<1, 64, 0, stream>>>(counts, offs);
    scatter_kernel<<<T_TOK / 512, 256, 0, stream>>>(eIdx, offs, fill, rowIdx, slot);
    // GEMM1: h = relu(x_gathered @ W1 + b1)   [rows, 2048], K=1024
    moe_gemm_kernel<D_DIM, H_DIM, true, true>
        <<<dim3(H_DIM / 128, T_TOK / 128, E_NUM), 256, 0, stream>>>(
            Xb, W1t, b1, Hb, counts, offs, rowIdx);
    // GEMM2: y = h @ W2 + b2   [rows, 1024], K=2048
    moe_gemm_kernel<H_DIM, D_DIM, false, false>
        <<<dim3(D_DIM / 128, T_TOK / 128, E_NUM), 256, 0, stream>>>(
            Hb, W2t, b2, Yb, counts, offs, (const int*)nullptr);
    combine_kernel<<<T_TOK, 256, 0, stream>>>(Yb, slot, wgt, out);
}